// Round 5
// baseline (256.554 us; speedup 1.0000x reference)
//
#include <hip/hip_runtime.h>

// ContourIntegrationLayer: depthwise 3x3 conv (center tap zeroed) + residual.
// x: [32,56,56,256] fp32 NHWC, kernel: [3,3,256] fp32.
//
// Model (R1-R3): the kernel is bound by the per-CU vector-memory service
// rate (~32 cyc per 1 KB wave-instr); R1 saturated it with 392 waves/CU.
// Coarsening (R2/R3) reduced instrs but broke TLP/ILP latency hiding and
// regressed. R4: keep 1 output/thread + full wave count; eliminate the 8
// kernel-tap global re-reads by staging taps in LDS and reading them into
// registers once per thread -> 10 vmem instrs/wave instead of 18.
// __launch_bounds__(256,4): 128-VGPR budget so kv[8]+xw[9] stay live and
// all 9 x-loads issue before the first s_waitcnt (R2 failed at the 64-cap).

#define BB 32
#define HH 56
#define WW 56
#define C4 64          // 256 channels / 4 per float4
#define NXCD 8

__global__ __launch_bounds__(256, 4) void contour_kernel(
    const float4* __restrict__ x,     // [B*H*W*C4]
    const float4* __restrict__ kern,  // [9*C4]
    float4* __restrict__ out)         // [B*H*W*C4]
{
    // Stage the 9 KB kernel table in LDS once per block (off the vmem pipe).
    __shared__ float4 klds[9 * C4];
    for (int i = threadIdx.x; i < 9 * C4; i += 256) klds[i] = kern[i];
    __syncthreads();

    // XCD swizzle: contiguous chunk per XCD (25088 = 8 * 3136 blocks; 3136
    // blocks = exactly 4 images -> zero cross-XCD x sharing).
    const int per_xcd = gridDim.x / NXCD;
    const int blk = (blockIdx.x % NXCD) * per_xcd + blockIdx.x / NXCD;

    const int idx = blk * 256 + threadIdx.x;   // ((b*H+h)*W + w)*C4 + c4
    const int c4 = idx & (C4 - 1);
    int t = idx >> 6;
    const int w = t % WW;
    t /= WW;
    const int h = t % HH;
    const int b = t / HH;

    // Kernel taps LDS -> registers, once (center tap dead). 8 x b128 reads.
    float4 kv[9];
    #pragma unroll
    for (int i = 0; i < 9; ++i)
        if (i != 4) kv[i] = klds[i * C4 + c4];

    // 3x3 x-window: issue all loads upfront (wave-uniform border predicates).
    const float4 zero = make_float4(0.f, 0.f, 0.f, 0.f);
    float4 xw[9];
    #pragma unroll
    for (int r = 0; r < 3; ++r) {
        const int hh = h - 1 + r;
        const bool hok = (hh >= 0) & (hh < HH);
        #pragma unroll
        for (int c = 0; c < 3; ++c) {
            const int ww = w - 1 + c;
            const bool ok = hok & (ww >= 0) & (ww < WW);
            xw[r * 3 + c] = ok ? x[((b * HH + hh) * WW + ww) * C4 + c4] : zero;
        }
    }

    float4 acc = xw[4];   // residual (center pixel; its tap is masked)
    #pragma unroll
    for (int i = 0; i < 9; ++i) {
        if (i == 4) continue;
        acc.x += xw[i].x * kv[i].x;
        acc.y += xw[i].y * kv[i].y;
        acc.z += xw[i].z * kv[i].z;
        acc.w += xw[i].w * kv[i].w;
    }
    out[idx] = acc;
}

extern "C" void kernel_launch(void* const* d_in, const int* in_sizes, int n_in,
                              void* d_out, int out_size, void* d_ws, size_t ws_size,
                              hipStream_t stream) {
    const float4* x    = (const float4*)d_in[0];
    const float4* kern = (const float4*)d_in[1];
    float4* out        = (float4*)d_out;

    const int total = BB * HH * WW * C4;           // 6,422,528 threads
    const int block = 256;
    const int grid  = total / block;               // 25,088 blocks (8 * 3136)
    contour_kernel<<<grid, block, 0, stream>>>(x, kern, out);
}